// Round 3
// baseline (83466.687 us; speedup 1.0000x reference)
//
#include <hip/hip_runtime.h>
#include <math.h>

#define T_STEPS 512
#define IN_DIM  17
#define HID     512
#define LAT     256
#define BT      16
#define NTH     512

typedef __attribute__((ext_vector_type(8))) _Float16 half8;
typedef __attribute__((ext_vector_type(4))) float    f32x4;

// ---------------- workspace layout (byte offsets, 16B-aligned) ----------
// wAll : unified GI+GH B-frags, wave-contiguous:
//        [w8:8][kt:24][g:3][jt:4][lane:64][j:8] fp16   (2,359,296 B)
//        kt<8: w_ih k=kt*32.. ; kt>=8: w_hh k=(kt-8)*32..
// w2P  : E2 B-frags [16 nt][8 kt][64][8] fp16          (131,072 B)
// w1P  : E1 B-frags [16 nt][64][8] fp16 (k>=17 zero)   (16,384 B)
// headP: head B-frags [16 kt][64][8] fp16 (n>=10 zero) (16,384 B)
// w256 : w_ih[:,256] fp32 [1536]
// bcomb: fp32 [1536]; bhn: fp32 [512]
#define OFF_WALL  0
#define OFF_W2P   2359296
#define OFF_W1P   2490368
#define OFF_HEADP 2506752
#define OFF_W256  2523136
#define OFF_BCOMB 2529280
#define OFF_BHN   2535424

static __device__ inline unsigned short f2h(float f) {
    union { _Float16 h; unsigned short u; } cv;
    cv.h = (_Float16)f;
    return cv.u;
}

__global__ void pack_kernel(const float* __restrict__ enc_w1,
                            const float* __restrict__ enc_w2,
                            const float* __restrict__ w_ih,
                            const float* __restrict__ w_hh,
                            const float* __restrict__ b_ih,
                            const float* __restrict__ b_hh,
                            const float* __restrict__ q_w,
                            const float* __restrict__ v_w,
                            const float* __restrict__ c_w,
                            unsigned char* __restrict__ ws) {
    unsigned short* wAll  = (unsigned short*)(ws + OFF_WALL);
    unsigned short* w2P   = (unsigned short*)(ws + OFF_W2P);
    unsigned short* w1P   = (unsigned short*)(ws + OFF_W1P);
    unsigned short* headP = (unsigned short*)(ws + OFF_HEADP);
    float* w256  = (float*)(ws + OFF_W256);
    float* bcomb = (float*)(ws + OFF_BCOMB);
    float* bhn   = (float*)(ws + OFF_BHN);

    const int tid = blockIdx.x * blockDim.x + threadIdx.x;
    const int stride = gridDim.x * blockDim.x;

    for (int idx = tid; idx < 8 * 24 * 3 * 4 * 64 * 8; idx += stride) {  // wAll
        int j = idx & 7, l = (idx >> 3) & 63;
        int r = idx >> 9;
        int jt = r & 3, g = (r >> 2) % 3, kt = (r / 12) % 24, w8 = r / 288;
        int nt  = w8 * 4 + jt;
        int row = g * 512 + nt * 16 + (l & 15);
        int kk  = ((l >> 4) & 3) * 8 + j;
        float v;
        if (kt < 8) v = w_ih[(size_t)row * 257 + (kt * 32 + kk)];
        else        v = w_hh[(size_t)row * 512 + ((kt - 8) * 32 + kk)];
        wAll[idx] = f2h(v);
    }
    for (int idx = tid; idx < 16 * 8 * 64 * 8; idx += stride) {          // w2P
        int j = idx & 7, l = (idx >> 3) & 63, kt = (idx >> 9) & 7, nt = idx >> 12;
        int n = nt * 16 + (l & 15);
        int k = kt * 32 + ((l >> 4) & 3) * 8 + j;
        w2P[idx] = f2h(enc_w2[(size_t)n * 256 + k]);
    }
    for (int idx = tid; idx < 16 * 64 * 8; idx += stride) {              // w1P
        int j = idx & 7, l = (idx >> 3) & 63, nt = idx >> 9;
        int n = nt * 16 + (l & 15);
        int k = ((l >> 4) & 3) * 8 + j;
        w1P[idx] = (k < IN_DIM) ? f2h(enc_w1[(size_t)n * IN_DIM + k]) : (unsigned short)0;
    }
    for (int idx = tid; idx < 16 * 64 * 8; idx += stride) {              // headP
        int j = idx & 7, l = (idx >> 3) & 63, kt = idx >> 9;
        int d = l & 15;
        int k = kt * 32 + ((l >> 4) & 3) * 8 + j;
        float v = 0.f;
        if (d < 4)       v = q_w[(size_t)d * HID + k];
        else if (d < 7)  v = v_w[(size_t)(d - 4) * HID + k];
        else if (d < 10) v = c_w[(size_t)(d - 7) * HID + k];
        headP[idx] = f2h(v);
    }
    for (int idx = tid; idx < 1536; idx += stride) {
        w256[idx]  = w_ih[(size_t)idx * 257 + 256];
        bcomb[idx] = (idx < 1024) ? (b_ih[idx] + b_hh[idx]) : b_ih[idx];
    }
    for (int idx = tid; idx < 512; idx += stride) bhn[idx] = b_hh[1024 + idx];
}

#define GS_WAVE  (24 * 12 * 512)    // halfs per wave slice of wAll
#define MFMA16(a, b, c) __builtin_amdgcn_mfma_f32_16x16x32_f16((a), (b), (c), 0, 0, 0)

__global__ __launch_bounds__(NTH, 2)
void imu_mfma3_kernel(const float* __restrict__ x,
                      const float* __restrict__ h0,
                      const float* __restrict__ enc_b1,
                      const float* __restrict__ enc_b2,
                      const float* __restrict__ q_b,
                      const float* __restrict__ v_b,
                      const float* __restrict__ c_b,
                      const unsigned char* __restrict__ ws,
                      float* __restrict__ out)
{
    __shared__ __align__(16) unsigned short xbf[16][32];
    __shared__ __align__(16) float          xf[4][16];
    __shared__ __align__(16) unsigned short z1bf[16][264];
    __shared__ __align__(16) unsigned short actL[16][776];   // 0..255 lat, 256..767 h
    __shared__ __align__(16) unsigned short w1L[16 * 64 * 8];
    __shared__ __align__(16) unsigned short headL[16 * 64 * 8];
    __shared__ __align__(16) float          sdotP[8][16][17];
    __shared__ float eb1L[256], eb2L[256], bcombL[1536], bhnL[512], w256L[1536];

    const _Float16* wAll  = (const _Float16*)(ws + OFF_WALL);
    const unsigned short* w2P   = (const unsigned short*)(ws + OFF_W2P);
    const unsigned short* w1P   = (const unsigned short*)(ws + OFF_W1P);
    const unsigned short* headP = (const unsigned short*)(ws + OFF_HEADP);
    const float* w256g = (const float*)(ws + OFF_W256);
    const float* bcmg  = (const float*)(ws + OFF_BCOMB);
    const float* bhng  = (const float*)(ws + OFF_BHN);

    const int t   = threadIdx.x;
    const int w   = t >> 6;
    const int l   = t & 63;
    const int l15 = l & 15;
    const int lq  = (l >> 4) & 3;
    const int b0  = blockIdx.x * BT;

    // ---- one-time init ----
    for (int idx = t; idx < 16 * 64 * 8; idx += NTH) { w1L[idx] = w1P[idx]; headL[idx] = headP[idx]; }
    for (int idx = t; idx < 256; idx += NTH) { eb1L[idx] = enc_b1[idx]; eb2L[idx] = enc_b2[idx]; }
    for (int idx = t; idx < 1536; idx += NTH) { bcombL[idx] = bcmg[idx]; w256L[idx] = w256g[idx]; }
    for (int idx = t; idx < 512; idx += NTH) bhnL[idx] = bhng[idx];
    for (int idx = t; idx < 240; idx += NTH) { int b = idx / 15, k = 17 + idx % 15; xbf[b][k] = 0; }
    for (int idx = t; idx < 16 * 512; idx += NTH) {
        int b = idx >> 9, k = idx & 511;
        actL[b][256 + k] = f2h(h0[(size_t)(b0 + b) * HID + k]);
    }
    // h_old fp32 persistent in registers: thread owns (m=lq*4+i, jd=w*64+jt*16+l15)
    float ho[4][4];
    #pragma unroll
    for (int jt = 0; jt < 4; ++jt)
        #pragma unroll
        for (int i = 0; i < 4; ++i)
            ho[jt][i] = h0[(size_t)(b0 + lq * 4 + i) * HID + (w * 64 + jt * 16 + l15)];

    // x(0) into LDS
    {
        const int xb = t / 17, xk = t % 17;
        if (t < 272) {
            float v = x[((size_t)(b0 + xb) * T_STEPS + 0) * IN_DIM + xk];
            xbf[xb][xk] = f2h(v);
            if (xk < 3)   xf[xk][xb] = v;
            if (xk == 16) xf[3][xb] = v;
        }
    }
    float dp0 = 0.f, dp1 = 0.f, dp2 = 0.f;
    float sax = 0.f, say = 0.f, saz = 0.f, sdt = 0.f;   // stashed x for deferred quat
    __syncthreads();

    const _Float16* wb = wAll + (size_t)w * GS_WAVE + (size_t)l * 8;

    for (int step = 0; step < T_STEPS; ++step) {
        float dtreg[4];
        // ================= P2: E1 + deferred quat(step-1) + stash =================
        {
            f32x4 a0 = {0.f,0.f,0.f,0.f}, a1 = {0.f,0.f,0.f,0.f};
            const int nt0 = 2 * w, nt1 = 2 * w + 1;
            half8 av  = *(const half8*)&xbf[l15][lq * 8];
            half8 bv0 = *(const half8*)&w1L[((size_t)nt0 * 64 + l) * 8];
            half8 bv1 = *(const half8*)&w1L[((size_t)nt1 * 64 + l) * 8];
            a0 = MFMA16(av, bv0, a0);
            a1 = MFMA16(av, bv1, a1);
            #pragma unroll
            for (int i = 0; i < 4; ++i) {
                int m = lq * 4 + i;
                int n0 = nt0 * 16 + l15, n1 = nt1 * 16 + l15;
                z1bf[m][n0] = f2h(fmaxf(a0[i] + eb1L[n0], 0.f));
                z1bf[m][n1] = f2h(fmaxf(a1[i] + eb1L[n1], 0.f));
            }
        }
        #pragma unroll
        for (int i = 0; i < 4; ++i) dtreg[i] = xf[3][lq * 4 + i];
        if (t < BT) {
            const int b = t;
            if (step > 0) {
                float s[10];
                #pragma unroll
                for (int d = 0; d < 10; ++d) {
                    float acc = 0.f;
                    #pragma unroll
                    for (int w8 = 0; w8 < 8; ++w8) acc += sdotP[w8][b][d];
                    s[d] = acc;
                }
                float q0 = s[0] + q_b[0], q1 = s[1] + q_b[1];
                float q2 = s[2] + q_b[2], q3 = s[3] + q_b[3];
                float nrm = fmaxf(sqrtf(q0*q0 + q1*q1 + q2*q2 + q3*q3), 1e-12f);
                float qw = q0/nrm, qx = q1/nrm, qy = q2/nrm, qz = q3/nrm;
                float vx = s[4] + v_b[0], vy = s[5] + v_b[1], vz = s[6] + v_b[2];
                float ex = s[7] + c_b[0], ey = s[8] + c_b[1], ez = s[9] + c_b[2];
                float xx = qx*qx, yy = qy*qy, zz = qz*qz;
                float xy = qx*qy, xz = qx*qz, yz = qy*qz;
                float wxq = qw*qx, wyq = qw*qy, wzq = qw*qz;
                float aw0 = (1.f - 2.f*(yy+zz))*sax + 2.f*(xy-wzq)*say + 2.f*(xz+wyq)*saz;
                float aw1 = 2.f*(xy+wzq)*sax + (1.f - 2.f*(xx+zz))*say + 2.f*(yz-wxq)*saz;
                float aw2 = 2.f*(xz-wyq)*sax + 2.f*(yz+wxq)*say + (1.f - 2.f*(xx+yy))*saz;
                float hdt2 = 0.5f * sdt * sdt;
                dp0 += vx*sdt + aw0*hdt2 + ex;
                dp1 += vy*sdt + aw1*hdt2 + ey;
                dp2 += vz*sdt + aw2*hdt2 + ez;
            }
            sax = xf[0][b]; say = xf[1][b]; saz = xf[2][b]; sdt = xf[3][b];
        }
        __syncthreads();

        // ================= P3: E2 -> lat into actL[.][0..255] =================
        {
            f32x4 e0 = {0.f,0.f,0.f,0.f}, e1 = {0.f,0.f,0.f,0.f};
            const int nt0 = 2 * w, nt1 = 2 * w + 1;
            #pragma unroll
            for (int kt = 0; kt < 8; ++kt) {
                half8 av  = *(const half8*)&z1bf[l15][kt * 32 + lq * 8];
                half8 bv0 = *(const half8*)(w2P + ((size_t)(nt0 * 8 + kt) * 64 + l) * 8);
                half8 bv1 = *(const half8*)(w2P + ((size_t)(nt1 * 8 + kt) * 64 + l) * 8);
                e0 = MFMA16(av, bv0, e0);
                e1 = MFMA16(av, bv1, e1);
            }
            #pragma unroll
            for (int i = 0; i < 4; ++i) {
                int m = lq * 4 + i;
                int n0 = nt0 * 16 + l15, n1 = nt1 * 16 + l15;
                actL[m][n0] = f2h(fmaxf(e0[i] + eb2L[n0], 0.f));
                actL[m][n1] = f2h(fmaxf(e1[i] + eb2L[n1], 0.f));
            }
        }
        __syncthreads();

        // ===== P4: unified GI(kt 0..7) + GH(kt 8..23), register double-buffered =====
        f32x4 aR[4], aZ[4], aNi[4], aNh[4];
        #pragma unroll
        for (int jt = 0; jt < 4; ++jt) {
            aR[jt]  = (f32x4){0.f,0.f,0.f,0.f}; aZ[jt]  = (f32x4){0.f,0.f,0.f,0.f};
            aNi[jt] = (f32x4){0.f,0.f,0.f,0.f}; aNh[jt] = (f32x4){0.f,0.f,0.f,0.f};
        }
        {
            half8 bufA[12], bufB[12], avA, avB;

#define LD12(buf, ktv)                                                         \
            _Pragma("unroll")                                                  \
            for (int q = 0; q < 12; ++q)                                       \
                buf[q] = *(const half8*)(wb + ((size_t)(ktv) * 12 + q) * 512);
#define LDACT(ktv) (*(const half8*)&actL[l15][(ktv) * 32 + lq * 8])
#define MFMA_GI(buf, av)                                                       \
            _Pragma("unroll")                                                  \
            for (int jt = 0; jt < 4; ++jt) {                                   \
                aR[jt]  = MFMA16(av, buf[jt],     aR[jt]);                     \
                aZ[jt]  = MFMA16(av, buf[4 + jt], aZ[jt]);                     \
                aNi[jt] = MFMA16(av, buf[8 + jt], aNi[jt]);                    \
            }
#define MFMA_GH(buf, av)                                                       \
            _Pragma("unroll")                                                  \
            for (int jt = 0; jt < 4; ++jt) {                                   \
                aR[jt]  = MFMA16(av, buf[jt],     aR[jt]);                     \
                aZ[jt]  = MFMA16(av, buf[4 + jt], aZ[jt]);                     \
                aNh[jt] = MFMA16(av, buf[8 + jt], aNh[jt]);                    \
            }

            LD12(bufA, 0); avA = LDACT(0);
            for (int kt = 0; kt < 8; kt += 2) {
                LD12(bufB, kt + 1); avB = LDACT(kt + 1);
                MFMA_GI(bufA, avA);
                LD12(bufA, kt + 2); avA = LDACT(kt + 2);   // kt+2<=8: first GH frag ok
                MFMA_GI(bufB, avB);
            }
            for (int kt = 8; kt < 24; kt += 2) {
                LD12(bufB, kt + 1); avB = LDACT(kt + 1);
                MFMA_GH(bufA, avA);
                if (kt + 2 < 24) { LD12(bufA, kt + 2); avA = LDACT(kt + 2); }
                MFMA_GH(bufB, avB);
            }
#undef LD12
#undef LDACT
#undef MFMA_GI
#undef MFMA_GH
        }
        __syncthreads();   // all waves done reading actL (lat + h_old)

        // ===== P5: gate nonlinearity + h update (regs) -> actL h region =====
        #pragma unroll
        for (int jt = 0; jt < 4; ++jt) {
            const int jd = w * 64 + jt * 16 + l15;
            float bR = bcombL[jd], bZ = bcombL[512 + jd];
            float bIN = bcombL[1024 + jd], bHN = bhnL[jd];
            float wr2 = w256L[jd], wz2 = w256L[512 + jd], wn2 = w256L[1024 + jd];
            #pragma unroll
            for (int i = 0; i < 4; ++i) {
                int m = lq * 4 + i;
                float dtv = dtreg[i];
                float gr = aR[jt][i]  + bR  + dtv * wr2;
                float gz = aZ[jt][i]  + bZ  + dtv * wz2;
                float gi = aNi[jt][i] + bIN + dtv * wn2;
                float gh = aNh[jt][i] + bHN;
                float r  = 1.f / (1.f + __expf(-gr));
                float zg = 1.f / (1.f + __expf(-gz));
                float narg = gi + r * gh;
                float n  = 1.f - 2.f / (__expf(2.f * narg) + 1.f);
                float hn = (1.f - zg) * n + zg * ho[jt][i];
                ho[jt][i] = hn;
                actL[m][256 + jd] = f2h(hn);
            }
        }
        __syncthreads();   // h_new visible

        // ===== P6: x prefetch (step+1) + heads MFMA + partial stores =====
        float xr = 0.f;
        const int xb = t / 17, xk = t % 17;
        const bool xv = (step + 1 < T_STEPS) && (t < 272);
        if (xv) xr = x[((size_t)(b0 + xb) * T_STEPS + (step + 1)) * IN_DIM + xk];
        {
            f32x4 hc = {0.f,0.f,0.f,0.f};
            const int ka = 2 * w, kb = 2 * w + 1;
            half8 a0 = *(const half8*)&actL[l15][256 + ka * 32 + lq * 8];
            half8 b0 = *(const half8*)&headL[((size_t)ka * 64 + l) * 8];
            half8 a1 = *(const half8*)&actL[l15][256 + kb * 32 + lq * 8];
            half8 b1 = *(const half8*)&headL[((size_t)kb * 64 + l) * 8];
            hc = MFMA16(a0, b0, hc);
            hc = MFMA16(a1, b1, hc);
            #pragma unroll
            for (int i = 0; i < 4; ++i) sdotP[w][lq * 4 + i][l15] = hc[i];
        }
        if (xv) {
            xbf[xb][xk] = f2h(xr);
            if (xk < 3)   xf[xk][xb] = xr;
            if (xk == 16) xf[3][xb] = xr;
        }
        __syncthreads();
    }

    // ===== epilogue: deferred quat for the last step =====
    if (t < BT) {
        const int b = t;
        float s[10];
        #pragma unroll
        for (int d = 0; d < 10; ++d) {
            float acc = 0.f;
            #pragma unroll
            for (int w8 = 0; w8 < 8; ++w8) acc += sdotP[w8][b][d];
            s[d] = acc;
        }
        float q0 = s[0] + q_b[0], q1 = s[1] + q_b[1];
        float q2 = s[2] + q_b[2], q3 = s[3] + q_b[3];
        float nrm = fmaxf(sqrtf(q0*q0 + q1*q1 + q2*q2 + q3*q3), 1e-12f);
        float qw = q0/nrm, qx = q1/nrm, qy = q2/nrm, qz = q3/nrm;
        float vx = s[4] + v_b[0], vy = s[5] + v_b[1], vz = s[6] + v_b[2];
        float ex = s[7] + c_b[0], ey = s[8] + c_b[1], ez = s[9] + c_b[2];
        float xx = qx*qx, yy = qy*qy, zz = qz*qz;
        float xy = qx*qy, xz = qx*qz, yz = qy*qz;
        float wxq = qw*qx, wyq = qw*qy, wzq = qw*qz;
        float aw0 = (1.f - 2.f*(yy+zz))*sax + 2.f*(xy-wzq)*say + 2.f*(xz+wyq)*saz;
        float aw1 = 2.f*(xy+wzq)*sax + (1.f - 2.f*(xx+zz))*say + 2.f*(yz-wxq)*saz;
        float aw2 = 2.f*(xz-wyq)*sax + 2.f*(yz+wxq)*say + (1.f - 2.f*(xx+yy))*saz;
        float hdt2 = 0.5f * sdt * sdt;
        dp0 += vx*sdt + aw0*hdt2 + ex;
        dp1 += vy*sdt + aw1*hdt2 + ey;
        dp2 += vz*sdt + aw2*hdt2 + ez;
        out[(size_t)(b0 + t) * 3 + 0] = dp0;
        out[(size_t)(b0 + t) * 3 + 1] = dp1;
        out[(size_t)(b0 + t) * 3 + 2] = dp2;
    }
}

extern "C" void kernel_launch(void* const* d_in, const int* in_sizes, int n_in,
                              void* d_out, int out_size, void* d_ws, size_t ws_size,
                              hipStream_t stream) {
    const float* x      = (const float*)d_in[0];
    const float* h0     = (const float*)d_in[1];
    const float* enc_w1 = (const float*)d_in[2];
    const float* enc_b1 = (const float*)d_in[3];
    const float* enc_w2 = (const float*)d_in[4];
    const float* enc_b2 = (const float*)d_in[5];
    const float* w_ih   = (const float*)d_in[6];
    const float* w_hh   = (const float*)d_in[7];
    const float* b_ih   = (const float*)d_in[8];
    const float* b_hh   = (const float*)d_in[9];
    const float* q_w    = (const float*)d_in[10];
    const float* q_b    = (const float*)d_in[11];
    const float* v_w    = (const float*)d_in[12];
    const float* v_b    = (const float*)d_in[13];
    const float* c_w    = (const float*)d_in[14];
    const float* c_b    = (const float*)d_in[15];
    unsigned char* ws = (unsigned char*)d_ws;
    float* out = (float*)d_out;

    hipLaunchKernelGGL(pack_kernel, dim3(1024), dim3(256), 0, stream,
                       enc_w1, enc_w2, w_ih, w_hh, b_ih, b_hh, q_w, v_w, c_w, ws);
    hipLaunchKernelGGL(imu_mfma3_kernel, dim3(4096 / BT), dim3(NTH), 0, stream,
                       x, h0, enc_b1, enc_b2, q_b, v_b, c_b, ws, out);
}

// Round 4
// 48418.015 us; speedup vs baseline: 1.7239x; 1.7239x over previous
//
#include <hip/hip_runtime.h>
#include <hip/hip_cooperative_groups.h>
#include <math.h>

namespace cg = cooperative_groups;

#define T_STEPS 512
#define IN_DIM  17
#define HID     512
#define LAT     256
#define BT      16
#define NTH     512

typedef __attribute__((ext_vector_type(8))) _Float16 half8;
typedef __attribute__((ext_vector_type(4))) float    f32x4;

// ---------------- workspace layout (byte offsets, 16B-aligned) ----------
// act  : [4096 rows][1280 cols] fp16. cols 0..255 = lat, 256..767 = h region0,
//        768..1279 = h region1.                      10,485,760 B
// wgP  : gate B-frags per slice: [s:32][kt:24][g:3][lane:64][j:8] fp16
//        kt<8: w_ih k=kt*32.. ; kt>=8: w_hh k=(kt-8)*32..      2,359,296 B
// w2P  : E2 B-frags [16 nt][8 kt][64][8] fp16                    131,072 B
// w1P  : E1 B-frags [16 nt][64][8] fp16 (k>=17 zero)              16,384 B
// headP: head B-frags [16 kt][64][8] fp16 (n>=10 zero)            16,384 B
// w256 : w_ih[:,256] fp32 [1536];  bcomb fp32[1536];  bhn fp32[512]
// dtbuf: fp32 [4096]
#define OFF_ACT   0
#define OFF_WG    10485760
#define OFF_W2P   12845056
#define OFF_W1P   12976128
#define OFF_HEADP 12992512
#define OFF_W256  13008896
#define OFF_BCOMB 13015040
#define OFF_BHN   13021184
#define OFF_DT    13023232

static __device__ inline unsigned short f2h(float f) {
    union { _Float16 h; unsigned short u; } cv;
    cv.h = (_Float16)f;
    return cv.u;
}

__global__ void pack_kernel(const float* __restrict__ enc_w1,
                            const float* __restrict__ enc_w2,
                            const float* __restrict__ w_ih,
                            const float* __restrict__ w_hh,
                            const float* __restrict__ b_ih,
                            const float* __restrict__ b_hh,
                            const float* __restrict__ q_w,
                            const float* __restrict__ v_w,
                            const float* __restrict__ c_w,
                            unsigned char* __restrict__ ws) {
    unsigned short* wgP   = (unsigned short*)(ws + OFF_WG);
    unsigned short* w2P   = (unsigned short*)(ws + OFF_W2P);
    unsigned short* w1P   = (unsigned short*)(ws + OFF_W1P);
    unsigned short* headP = (unsigned short*)(ws + OFF_HEADP);
    float* w256  = (float*)(ws + OFF_W256);
    float* bcomb = (float*)(ws + OFF_BCOMB);
    float* bhn   = (float*)(ws + OFF_BHN);

    const int tid = blockIdx.x * blockDim.x + threadIdx.x;
    const int stride = gridDim.x * blockDim.x;

    for (int idx = tid; idx < 32 * 24 * 3 * 64 * 8; idx += stride) {     // wgP
        int j = idx & 7, l = (idx >> 3) & 63;
        int r = idx >> 9;
        int g = r % 3; r /= 3;
        int kt = r % 24; int s = r / 24;
        int row = g * 512 + s * 16 + (l & 15);
        int kk  = ((l >> 4) & 3) * 8 + j;
        float v;
        if (kt < 8) v = w_ih[(size_t)row * 257 + (kt * 32 + kk)];
        else        v = w_hh[(size_t)row * 512 + ((kt - 8) * 32 + kk)];
        wgP[idx] = f2h(v);
    }
    for (int idx = tid; idx < 16 * 8 * 64 * 8; idx += stride) {          // w2P
        int j = idx & 7, l = (idx >> 3) & 63, kt = (idx >> 9) & 7, nt = idx >> 12;
        int n = nt * 16 + (l & 15);
        int k = kt * 32 + ((l >> 4) & 3) * 8 + j;
        w2P[idx] = f2h(enc_w2[(size_t)n * 256 + k]);
    }
    for (int idx = tid; idx < 16 * 64 * 8; idx += stride) {              // w1P
        int j = idx & 7, l = (idx >> 3) & 63, nt = idx >> 9;
        int n = nt * 16 + (l & 15);
        int k = ((l >> 4) & 3) * 8 + j;
        w1P[idx] = (k < IN_DIM) ? f2h(enc_w1[(size_t)n * IN_DIM + k]) : (unsigned short)0;
    }
    for (int idx = tid; idx < 16 * 64 * 8; idx += stride) {              // headP
        int j = idx & 7, l = (idx >> 3) & 63, kt = idx >> 9;
        int d = l & 15;
        int k = kt * 32 + ((l >> 4) & 3) * 8 + j;
        float v = 0.f;
        if (d < 4)       v = q_w[(size_t)d * HID + k];
        else if (d < 7)  v = v_w[(size_t)(d - 4) * HID + k];
        else if (d < 10) v = c_w[(size_t)(d - 7) * HID + k];
        headP[idx] = f2h(v);
    }
    for (int idx = tid; idx < 1536; idx += stride) {
        w256[idx]  = w_ih[(size_t)idx * 257 + 256];
        bcomb[idx] = (idx < 1024) ? (b_ih[idx] + b_hh[idx]) : b_ih[idx];
    }
    for (int idx = tid; idx < 512; idx += stride) bhn[idx] = b_hh[1024 + idx];
}

#define MFMA16(a, b, c) __builtin_amdgcn_mfma_f32_16x16x32_f16((a), (b), (c), 0, 0, 0)
#define ROWW 1280   // act row length in halfs

__global__ __launch_bounds__(NTH, 2)
void imu_coop_kernel(const float* __restrict__ x,
                     const float* __restrict__ h0,
                     const float* __restrict__ enc_b1,
                     const float* __restrict__ enc_b2,
                     const float* __restrict__ q_b,
                     const float* __restrict__ v_b,
                     const float* __restrict__ c_b,
                     unsigned char* __restrict__ ws,
                     float* __restrict__ out)
{
    cg::grid_group grid = cg::this_grid();

    __shared__ __align__(16) unsigned short wgL[24 * 3 * 64 * 8];   // 73,728 B
    __shared__ __align__(16) unsigned short xbf[16][32];
    __shared__ __align__(16) float          xf[4][16];
    __shared__ __align__(16) unsigned short z1bf[16][264];
    __shared__ __align__(16) float          sdotP[8][16][17];
    __shared__ float eb1L[256], eb2L[256];

    unsigned short* act = (unsigned short*)(ws + OFF_ACT);
    const unsigned short* wgP   = (const unsigned short*)(ws + OFF_WG);
    const unsigned short* w2P   = (const unsigned short*)(ws + OFF_W2P);
    const unsigned short* w1P   = (const unsigned short*)(ws + OFF_W1P);
    const unsigned short* headP = (const unsigned short*)(ws + OFF_HEADP);
    const float* w256g = (const float*)(ws + OFF_W256);
    const float* bcmg  = (const float*)(ws + OFF_BCOMB);
    const float* bhng  = (const float*)(ws + OFF_BHN);
    float* dtbuf = (float*)(ws + OFF_DT);

    const int t    = threadIdx.x;
    const int w    = t >> 6;
    const int l    = t & 63;
    const int l15  = l & 15;
    const int lq   = (l >> 4) & 3;
    const int blk  = blockIdx.x;
    const int s_sl = blk >> 3;       // gate slice 0..31
    const int g    = blk & 7;        // batch group 0..7 (same-XCD heuristic)
    const int eb0  = blk * BT;       // encoder/heads batch ownership

    // ---- one-time init ----
    {   // gate weight slice -> LDS (uint4 copies)
        const uint4* src = (const uint4*)(wgP + (size_t)s_sl * (24 * 3 * 64 * 8));
        uint4* dst = (uint4*)wgL;
        for (int i = t; i < 24 * 3 * 64; i += NTH) dst[i] = src[i];
    }
    for (int idx = t; idx < 256; idx += NTH) { eb1L[idx] = enc_b1[idx]; eb2L[idx] = enc_b2[idx]; }
    for (int idx = t; idx < 16 * 32; idx += NTH) xbf[idx >> 5][idx & 31] = 0;
    for (int idx = t; idx < 16 * 512; idx += NTH) {           // h0 -> act region 0
        int b = idx >> 9, k = idx & 511;
        act[(size_t)(eb0 + b) * ROWW + 256 + k] = f2h(h0[(size_t)(eb0 + b) * HID + k]);
    }
    const int jd = s_sl * 16 + l15;                            // owned h-dim
    float ho[4][4];                                            // h_old fp32 in regs
    #pragma unroll
    for (int mt = 0; mt < 4; ++mt)
        #pragma unroll
        for (int i = 0; i < 4; ++i)
            ho[mt][i] = h0[(size_t)(g * 512 + w * 64 + mt * 16 + lq * 4 + i) * HID + jd];
    const float bR  = bcmg[jd],        bZ  = bcmg[512 + jd];
    const float bIN = bcmg[1024 + jd], bHN = bhng[jd];
    const float wr2 = w256g[jd], wz2 = w256g[512 + jd], wn2 = w256g[1024 + jd];

    float dp0 = 0.f, dp1 = 0.f, dp2 = 0.f;
    float sax = 0.f, say = 0.f, saz = 0.f, sdt = 0.f;
    __syncthreads();

    const size_t abase = ((size_t)(g * 512 + w * 64) + l15) * ROWW + lq * 8;

    for (int step = 0; step < T_STEPS; ++step) {
        const int rp = step & 1;          // h read region
        const int wp = rp ^ 1;            // h write region

        // ========== Phase 1: x load + heads(step-1) + encoder ==========
        float xr = 0.f;
        const int xb = t / 17, xk = t % 17;
        const bool xv = (t < 272);
        if (xv) xr = x[((size_t)(eb0 + xb) * T_STEPS + step) * IN_DIM + xk];

        {   // heads MFMA on h(step-1) (region rp), rows eb0..eb0+15
            f32x4 hc = {0.f, 0.f, 0.f, 0.f};
            const int colh = 256 + rp * 512;
            const int ka = 2 * w, kb = 2 * w + 1;
            half8 a0 = *(const half8*)(act + (size_t)(eb0 + l15) * ROWW + colh + ka * 32 + lq * 8);
            half8 b0 = *(const half8*)(headP + ((size_t)ka * 64 + l) * 8);
            half8 a1 = *(const half8*)(act + (size_t)(eb0 + l15) * ROWW + colh + kb * 32 + lq * 8);
            half8 b1 = *(const half8*)(headP + ((size_t)kb * 64 + l) * 8);
            hc = MFMA16(a0, b0, hc);
            hc = MFMA16(a1, b1, hc);
            #pragma unroll
            for (int i = 0; i < 4; ++i) sdotP[w][lq * 4 + i][l15] = hc[i];
        }
        if (xv) {
            xbf[xb][xk] = f2h(xr);
            if (xk < 3)   xf[xk][xb] = xr;
            if (xk == 16) { xf[3][xb] = xr; dtbuf[eb0 + xb] = xr; }
        }
        __syncthreads();

        if (t < BT) {
            const int b = t;
            if (step > 0) {
                float s[10];
                #pragma unroll
                for (int d = 0; d < 10; ++d) {
                    float acc = 0.f;
                    #pragma unroll
                    for (int w8 = 0; w8 < 8; ++w8) acc += sdotP[w8][b][d];
                    s[d] = acc;
                }
                float q0 = s[0] + q_b[0], q1 = s[1] + q_b[1];
                float q2 = s[2] + q_b[2], q3 = s[3] + q_b[3];
                float nrm = fmaxf(sqrtf(q0*q0 + q1*q1 + q2*q2 + q3*q3), 1e-12f);
                float qw = q0/nrm, qx = q1/nrm, qy = q2/nrm, qz = q3/nrm;
                float vx = s[4] + v_b[0], vy = s[5] + v_b[1], vz = s[6] + v_b[2];
                float ex = s[7] + c_b[0], ey = s[8] + c_b[1], ez = s[9] + c_b[2];
                float xx = qx*qx, yy = qy*qy, zz = qz*qz;
                float xy = qx*qy, xz = qx*qz, yz = qy*qz;
                float wxq = qw*qx, wyq = qw*qy, wzq = qw*qz;
                float aw0 = (1.f - 2.f*(yy+zz))*sax + 2.f*(xy-wzq)*say + 2.f*(xz+wyq)*saz;
                float aw1 = 2.f*(xy+wzq)*sax + (1.f - 2.f*(xx+zz))*say + 2.f*(yz-wxq)*saz;
                float aw2 = 2.f*(xz-wyq)*sax + 2.f*(yz+wxq)*say + (1.f - 2.f*(xx+yy))*saz;
                float hdt2 = 0.5f * sdt * sdt;
                dp0 += vx*sdt + aw0*hdt2 + ex;
                dp1 += vy*sdt + aw1*hdt2 + ey;
                dp2 += vz*sdt + aw2*hdt2 + ez;
            }
            sax = xf[0][t]; say = xf[1][t]; saz = xf[2][t]; sdt = xf[3][t];
        }

        {   // E1: z1 = relu(x @ w1T + b1)
            f32x4 a0 = {0.f,0.f,0.f,0.f}, a1 = {0.f,0.f,0.f,0.f};
            const int nt0 = 2 * w, nt1 = 2 * w + 1;
            half8 av  = *(const half8*)&xbf[l15][lq * 8];
            half8 bv0 = *(const half8*)(w1P + ((size_t)nt0 * 64 + l) * 8);
            half8 bv1 = *(const half8*)(w1P + ((size_t)nt1 * 64 + l) * 8);
            a0 = MFMA16(av, bv0, a0);
            a1 = MFMA16(av, bv1, a1);
            #pragma unroll
            for (int i = 0; i < 4; ++i) {
                int m = lq * 4 + i;
                int n0 = nt0 * 16 + l15, n1 = nt1 * 16 + l15;
                z1bf[m][n0] = f2h(fmaxf(a0[i] + eb1L[n0], 0.f));
                z1bf[m][n1] = f2h(fmaxf(a1[i] + eb1L[n1], 0.f));
            }
        }
        __syncthreads();

        {   // E2: lat = relu(z1 @ w2T + b2) -> act lat cols (global)
            f32x4 e0 = {0.f,0.f,0.f,0.f}, e1 = {0.f,0.f,0.f,0.f};
            const int nt0 = 2 * w, nt1 = 2 * w + 1;
            #pragma unroll
            for (int kt = 0; kt < 8; ++kt) {
                half8 av  = *(const half8*)&z1bf[l15][kt * 32 + lq * 8];
                half8 bv0 = *(const half8*)(w2P + ((size_t)(nt0 * 8 + kt) * 64 + l) * 8);
                half8 bv1 = *(const half8*)(w2P + ((size_t)(nt1 * 8 + kt) * 64 + l) * 8);
                e0 = MFMA16(av, bv0, e0);
                e1 = MFMA16(av, bv1, e1);
            }
            #pragma unroll
            for (int i = 0; i < 4; ++i) {
                int m = lq * 4 + i;
                int n0 = nt0 * 16 + l15, n1 = nt1 * 16 + l15;
                act[(size_t)(eb0 + m) * ROWW + n0] = f2h(fmaxf(e0[i] + eb2L[n0], 0.f));
                act[(size_t)(eb0 + m) * ROWW + n1] = f2h(fmaxf(e1[i] + eb2L[n1], 0.f));
            }
        }
        grid.sync();   // lat(s), dt(s) visible; heads done reading h(s-1)

        // ========== Phase 2: gate GEMM M=512,N=48,K=768 + h update ==========
        {
            f32x4 aR[4], aZ[4], aNi[4], aNh[4];
            #pragma unroll
            for (int mt = 0; mt < 4; ++mt) {
                aR[mt]  = (f32x4){0.f,0.f,0.f,0.f}; aZ[mt]  = (f32x4){0.f,0.f,0.f,0.f};
                aNi[mt] = (f32x4){0.f,0.f,0.f,0.f}; aNh[mt] = (f32x4){0.f,0.f,0.f,0.f};
            }
            const int colh = 256 + rp * 512;
            half8 aF[2][4], bF[2][3];
            {
                #pragma unroll
                for (int mt = 0; mt < 4; ++mt)
                    aF[0][mt] = *(const half8*)(act + abase + mt * (16 * ROWW) + 0);
                #pragma unroll
                for (int gg = 0; gg < 3; ++gg)
                    bF[0][gg] = *(const half8*)&wgL[((size_t)(0 * 3 + gg) * 64 + l) * 8];
            }
            #pragma unroll
            for (int kt = 0; kt < 24; ++kt) {
                const int cur = kt & 1, nxt = cur ^ 1;
                if (kt < 23) {
                    const int knx = kt + 1;
                    const int cnx = (knx < 8) ? knx * 32 : colh + (knx - 8) * 32;
                    #pragma unroll
                    for (int mt = 0; mt < 4; ++mt)
                        aF[nxt][mt] = *(const half8*)(act + abase + mt * (16 * ROWW) + cnx);
                    #pragma unroll
                    for (int gg = 0; gg < 3; ++gg)
                        bF[nxt][gg] = *(const half8*)&wgL[((size_t)(knx * 3 + gg) * 64 + l) * 8];
                }
                #pragma unroll
                for (int mt = 0; mt < 4; ++mt) {
                    aR[mt] = MFMA16(aF[cur][mt], bF[cur][0], aR[mt]);
                    aZ[mt] = MFMA16(aF[cur][mt], bF[cur][1], aZ[mt]);
                    if (kt < 8) aNi[mt] = MFMA16(aF[cur][mt], bF[cur][2], aNi[mt]);
                    else        aNh[mt] = MFMA16(aF[cur][mt], bF[cur][2], aNh[mt]);
                }
            }
            // gate nonlinearity + h_new
            #pragma unroll
            for (int mt = 0; mt < 4; ++mt) {
                #pragma unroll
                for (int i = 0; i < 4; ++i) {
                    const int row = g * 512 + w * 64 + mt * 16 + lq * 4 + i;
                    float dtv = dtbuf[row];
                    float gr = aR[mt][i]  + bR  + dtv * wr2;
                    float gz = aZ[mt][i]  + bZ  + dtv * wz2;
                    float gi = aNi[mt][i] + bIN + dtv * wn2;
                    float gh = aNh[mt][i] + bHN;
                    float r  = 1.f / (1.f + __expf(-gr));
                    float zg = 1.f / (1.f + __expf(-gz));
                    float narg = gi + r * gh;
                    float n  = 1.f - 2.f / (__expf(2.f * narg) + 1.f);
                    float hn = (1.f - zg) * n + zg * ho[mt][i];
                    ho[mt][i] = hn;
                    act[(size_t)row * ROWW + 256 + wp * 512 + jd] = f2h(hn);
                }
            }
        }
        grid.sync();   // h(s) visible everywhere
    }

    // ========== epilogue: heads for step T-1 (h in region 0) ==========
    {
        f32x4 hc = {0.f, 0.f, 0.f, 0.f};
        const int colh = 256;   // region 0 = (T_STEPS)&1 ^ ... final write region
        const int ka = 2 * w, kb = 2 * w + 1;
        half8 a0 = *(const half8*)(act + (size_t)(eb0 + l15) * ROWW + colh + ka * 32 + lq * 8);
        half8 b0 = *(const half8*)(headP + ((size_t)ka * 64 + l) * 8);
        half8 a1 = *(const half8*)(act + (size_t)(eb0 + l15) * ROWW + colh + kb * 32 + lq * 8);
        half8 b1 = *(const half8*)(headP + ((size_t)kb * 64 + l) * 8);
        hc = MFMA16(a0, b0, hc);
        hc = MFMA16(a1, b1, hc);
        #pragma unroll
        for (int i = 0; i < 4; ++i) sdotP[w][lq * 4 + i][l15] = hc[i];
    }
    __syncthreads();
    if (t < BT) {
        const int b = t;
        float s[10];
        #pragma unroll
        for (int d = 0; d < 10; ++d) {
            float acc = 0.f;
            #pragma unroll
            for (int w8 = 0; w8 < 8; ++w8) acc += sdotP[w8][b][d];
            s[d] = acc;
        }
        float q0 = s[0] + q_b[0], q1 = s[1] + q_b[1];
        float q2 = s[2] + q_b[2], q3 = s[3] + q_b[3];
        float nrm = fmaxf(sqrtf(q0*q0 + q1*q1 + q2*q2 + q3*q3), 1e-12f);
        float qw = q0/nrm, qx = q1/nrm, qy = q2/nrm, qz = q3/nrm;
        float vx = s[4] + v_b[0], vy = s[5] + v_b[1], vz = s[6] + v_b[2];
        float ex = s[7] + c_b[0], ey = s[8] + c_b[1], ez = s[9] + c_b[2];
        float xx = qx*qx, yy = qy*qy, zz = qz*qz;
        float xy = qx*qy, xz = qx*qz, yz = qy*qz;
        float wxq = qw*qx, wyq = qw*qy, wzq = qw*qz;
        float aw0 = (1.f - 2.f*(yy+zz))*sax + 2.f*(xy-wzq)*say + 2.f*(xz+wyq)*saz;
        float aw1 = 2.f*(xy+wzq)*sax + (1.f - 2.f*(xx+zz))*say + 2.f*(yz-wxq)*saz;
        float aw2 = 2.f*(xz-wyq)*sax + 2.f*(yz+wxq)*say + (1.f - 2.f*(xx+yy))*saz;
        float hdt2 = 0.5f * sdt * sdt;
        dp0 += vx*sdt + aw0*hdt2 + ex;
        dp1 += vy*sdt + aw1*hdt2 + ey;
        dp2 += vz*sdt + aw2*hdt2 + ez;
        out[(size_t)(eb0 + t) * 3 + 0] = dp0;
        out[(size_t)(eb0 + t) * 3 + 1] = dp1;
        out[(size_t)(eb0 + t) * 3 + 2] = dp2;
    }
}

extern "C" void kernel_launch(void* const* d_in, const int* in_sizes, int n_in,
                              void* d_out, int out_size, void* d_ws, size_t ws_size,
                              hipStream_t stream) {
    const float* x      = (const float*)d_in[0];
    const float* h0     = (const float*)d_in[1];
    const float* enc_w1 = (const float*)d_in[2];
    const float* enc_b1 = (const float*)d_in[3];
    const float* enc_w2 = (const float*)d_in[4];
    const float* enc_b2 = (const float*)d_in[5];
    const float* w_ih   = (const float*)d_in[6];
    const float* w_hh   = (const float*)d_in[7];
    const float* b_ih   = (const float*)d_in[8];
    const float* b_hh   = (const float*)d_in[9];
    const float* q_w    = (const float*)d_in[10];
    const float* q_b    = (const float*)d_in[11];
    const float* v_w    = (const float*)d_in[12];
    const float* v_b    = (const float*)d_in[13];
    const float* c_w    = (const float*)d_in[14];
    const float* c_b    = (const float*)d_in[15];
    unsigned char* ws = (unsigned char*)d_ws;
    float* out = (float*)d_out;

    hipLaunchKernelGGL(pack_kernel, dim3(2048), dim3(256), 0, stream,
                       enc_w1, enc_w2, w_ih, w_hh, b_ih, b_hh, q_w, v_w, c_w, ws);

    void* args[] = { (void*)&x, (void*)&h0, (void*)&enc_b1, (void*)&enc_b2,
                     (void*)&q_b, (void*)&v_b, (void*)&c_b, (void*)&ws, (void*)&out };
    hipLaunchCooperativeKernel((void*)imu_coop_kernel, dim3(256), dim3(NTH),
                               args, 0, stream);
}

// Round 6
// 27327.731 us; speedup vs baseline: 3.0543x; 1.7718x over previous
//
#include <hip/hip_runtime.h>
#include <math.h>

#define T_STEPS 512
#define IN_DIM  17
#define HID     512
#define LAT     256
#define BT      16
#define NTH     512
#define CHUNK   4

typedef __attribute__((ext_vector_type(8))) _Float16 half8;
typedef __attribute__((ext_vector_type(4))) float    f32x4;

// ---------------- workspace layout (byte offsets, 16B-aligned) ----------
// hbuf0/1 : [4096][512] fp16 h double buffer            4,194,304 each
// latbuf  : [4096][4 cslot][256] fp16                   8,388,608
// wgP     : gate B-frags [s:32][kt:24][g:3][64][8] fp16 2,359,296
// w2P     : E2 B-frags [16 nt][8 kt][64][8] fp16          131,072
// w1P     : E1 B-frags [16 nt][64][8] fp16                 16,384
// headP   : head B-frags [16 kt][64][8] fp16               16,384
// w256/bcomb fp32[1536]; bhn fp32[512]
// dtbuf   : [4096][4] fp32                                  65,536
// ctr     : stepctr uint[8][512] + chunkctr uint[8][128]    20,480
#define OFF_HB0   0
#define OFF_HB1   4194304
#define OFF_LAT   8388608
#define OFF_WG    16777216
#define OFF_W2P   19136512
#define OFF_W1P   19267584
#define OFF_HEADP 19283968
#define OFF_W256  19300352
#define OFF_BCOMB 19306496
#define OFF_BHN   19312640
#define OFF_DT    19314688
#define OFF_CTR   19380224

static __device__ inline unsigned short f2h(float f) {
    union { _Float16 h; unsigned short u; } cv;
    cv.h = (_Float16)f;
    return cv.u;
}

__global__ void pack_kernel(const float* __restrict__ enc_w1,
                            const float* __restrict__ enc_w2,
                            const float* __restrict__ w_ih,
                            const float* __restrict__ w_hh,
                            const float* __restrict__ b_ih,
                            const float* __restrict__ b_hh,
                            const float* __restrict__ q_w,
                            const float* __restrict__ v_w,
                            const float* __restrict__ c_w,
                            const float* __restrict__ h0,
                            unsigned char* __restrict__ ws) {
    unsigned short* wgP   = (unsigned short*)(ws + OFF_WG);
    unsigned short* w2P   = (unsigned short*)(ws + OFF_W2P);
    unsigned short* w1P   = (unsigned short*)(ws + OFF_W1P);
    unsigned short* headP = (unsigned short*)(ws + OFF_HEADP);
    unsigned short* hb0   = (unsigned short*)(ws + OFF_HB0);
    float* w256  = (float*)(ws + OFF_W256);
    float* bcomb = (float*)(ws + OFF_BCOMB);
    float* bhn   = (float*)(ws + OFF_BHN);
    unsigned int* ctr = (unsigned int*)(ws + OFF_CTR);

    const int tid = blockIdx.x * blockDim.x + threadIdx.x;
    const int stride = gridDim.x * blockDim.x;

    for (int idx = tid; idx < 32 * 24 * 3 * 64 * 8; idx += stride) {     // wgP
        int j = idx & 7, l = (idx >> 3) & 63;
        int r = idx >> 9;
        int g = r % 3; r /= 3;
        int kt = r % 24; int s = r / 24;
        int row = g * 512 + s * 16 + (l & 15);
        int kk  = ((l >> 4) & 3) * 8 + j;
        float v;
        if (kt < 8) v = w_ih[(size_t)row * 257 + (kt * 32 + kk)];
        else        v = w_hh[(size_t)row * 512 + ((kt - 8) * 32 + kk)];
        wgP[idx] = f2h(v);
    }
    for (int idx = tid; idx < 16 * 8 * 64 * 8; idx += stride) {          // w2P
        int j = idx & 7, l = (idx >> 3) & 63, kt = (idx >> 9) & 7, nt = idx >> 12;
        int n = nt * 16 + (l & 15);
        int k = kt * 32 + ((l >> 4) & 3) * 8 + j;
        w2P[idx] = f2h(enc_w2[(size_t)n * 256 + k]);
    }
    for (int idx = tid; idx < 16 * 64 * 8; idx += stride) {              // w1P
        int j = idx & 7, l = (idx >> 3) & 63, nt = idx >> 9;
        int n = nt * 16 + (l & 15);
        int k = ((l >> 4) & 3) * 8 + j;
        w1P[idx] = (k < IN_DIM) ? f2h(enc_w1[(size_t)n * IN_DIM + k]) : (unsigned short)0;
    }
    for (int idx = tid; idx < 16 * 64 * 8; idx += stride) {              // headP
        int j = idx & 7, l = (idx >> 3) & 63, kt = idx >> 9;
        int d = l & 15;
        int k = kt * 32 + ((l >> 4) & 3) * 8 + j;
        float v = 0.f;
        if (d < 4)       v = q_w[(size_t)d * HID + k];
        else if (d < 7)  v = v_w[(size_t)(d - 4) * HID + k];
        else if (d < 10) v = c_w[(size_t)(d - 7) * HID + k];
        headP[idx] = f2h(v);
    }
    for (int idx = tid; idx < 1536; idx += stride) {
        w256[idx]  = w_ih[(size_t)idx * 257 + 256];
        bcomb[idx] = (idx < 1024) ? (b_ih[idx] + b_hh[idx]) : b_ih[idx];
    }
    for (int idx = tid; idx < 512; idx += stride) bhn[idx] = b_hh[1024 + idx];
    for (int idx = tid; idx < 4096 * 512; idx += stride)                 // h0 -> hbuf0
        hb0[idx] = f2h(h0[idx]);
    for (int idx = tid; idx < 5120; idx += stride) ctr[idx] = 0;         // barriers
}

#define MFMA16(a, b, c) __builtin_amdgcn_mfma_f32_16x16x32_f16((a), (b), (c), 0, 0, 0)

// 32-block group barrier: counter-per-slot, never reset.
static __device__ inline void group_barrier(unsigned int* slot) {
    __syncthreads();                       // all waves' vmem drained (implied waitcnt)
    if (threadIdx.x == 0) {
        __threadfence();                   // release
        __hip_atomic_fetch_add(slot, 1u, __ATOMIC_RELEASE, __HIP_MEMORY_SCOPE_AGENT);
        while (__hip_atomic_load(slot, __ATOMIC_ACQUIRE, __HIP_MEMORY_SCOPE_AGENT) < 32u)
            __builtin_amdgcn_s_sleep(2);
        __threadfence();                   // acquire
    }
    __syncthreads();
}

__global__ __launch_bounds__(NTH, 2)
void imu_coop_kernel(const float* __restrict__ x,
                     const float* __restrict__ h0,
                     const float* __restrict__ enc_b1,
                     const float* __restrict__ enc_b2,
                     const float* __restrict__ q_b,
                     const float* __restrict__ v_b,
                     const float* __restrict__ c_b,
                     unsigned char* __restrict__ ws,
                     float* __restrict__ out)
{
    __shared__ __align__(16) unsigned short wgL[24 * 3 * 64 * 8];   // 73,728 B
    __shared__ __align__(16) unsigned short xbf64[64][32];          //  4,096 B
    __shared__ __align__(16) unsigned short z1bf64[64][264];        // 33,792 B
    __shared__ __align__(16) float          sdotP[8][16][17];       //  8,704 B
    __shared__ float eb1L[256], eb2L[256];

    unsigned short* hb[2] = { (unsigned short*)(ws + OFF_HB0),
                              (unsigned short*)(ws + OFF_HB1) };
    unsigned short*       latbuf = (unsigned short*)(ws + OFF_LAT);
    const unsigned short* wgP    = (const unsigned short*)(ws + OFF_WG);
    const unsigned short* w2P    = (const unsigned short*)(ws + OFF_W2P);
    const unsigned short* w1P    = (const unsigned short*)(ws + OFF_W1P);
    const unsigned short* headP  = (const unsigned short*)(ws + OFF_HEADP);
    const float* w256g = (const float*)(ws + OFF_W256);
    const float* bcmg  = (const float*)(ws + OFF_BCOMB);
    const float* bhng  = (const float*)(ws + OFF_BHN);
    float* dtbuf = (float*)(ws + OFF_DT);
    unsigned int* stepctr  = (unsigned int*)(ws + OFF_CTR) + (size_t)(blockIdx.x & 7) * 512;
    unsigned int* chunkctr = (unsigned int*)(ws + OFF_CTR + 16384) + (size_t)(blockIdx.x & 7) * 128;

    const int t    = threadIdx.x;
    const int w    = t >> 6;
    const int l    = t & 63;
    const int l15  = l & 15;
    const int lq   = (l >> 4) & 3;
    const int s_sl = blockIdx.x >> 3;            // gate N-slice 0..31
    const int g    = blockIdx.x & 7;             // batch group 0..7
    const int eb0  = g * 512 + s_sl * 16;        // encoder/heads rows (inside group!)

    const f32x4 fz = {0.f, 0.f, 0.f, 0.f};

    // ---- one-time init ----
    {
        const uint4* src = (const uint4*)(wgP + (size_t)s_sl * (24 * 3 * 64 * 8));
        uint4* dst = (uint4*)wgL;
        for (int i = t; i < 24 * 3 * 64; i += NTH) dst[i] = src[i];
    }
    for (int idx = t; idx < 256; idx += NTH) { eb1L[idx] = enc_b1[idx]; eb2L[idx] = enc_b2[idx]; }
    for (int idx = t; idx < 64 * 32; idx += NTH) xbf64[idx >> 5][idx & 31] = 0;

    const int jd = s_sl * 16 + l15;              // owned gate/h dim
    const float bR  = bcmg[jd],        bZ  = bcmg[512 + jd];
    const float bIN = bcmg[1024 + jd], bHN = bhng[jd];
    const float wr2 = w256g[jd], wz2 = w256g[512 + jd], wn2 = w256g[1024 + jd];

    float ho[4][4];                              // h_old fp32 in regs
    #pragma unroll
    for (int mt = 0; mt < 4; ++mt)
        #pragma unroll
        for (int i = 0; i < 4; ++i)
            ho[mt][i] = h0[(size_t)(g * 512 + w * 64 + mt * 16 + lq * 4 + i) * HID + jd];

    float dp0 = 0.f, dp1 = 0.f, dp2 = 0.f;
    __syncthreads();

    const size_t r0 = (size_t)(g * 512 + w * 64) + l15;   // A-frag row base (+mt*16)

    for (int s = 0; s < T_STEPS; ++s) {
        const int cs = s & 3;
        // ================= lat pre-phase, once per 4 steps =================
        if (cs == 0) {
            const int c = s >> 2;
            for (int idx = t; idx < 17 * 16 * CHUNK; idx += NTH) {
                int k = idx % 17, rem = idx / 17;
                int b = rem & 15, cc = rem >> 4;
                float v = x[((size_t)(eb0 + b) * T_STEPS + (c * 4 + cc)) * IN_DIM + k];
                xbf64[cc * 16 + b][k] = f2h(v);
                if (k == 16) dtbuf[(size_t)(eb0 + b) * 4 + cc] = v;
            }
            __syncthreads();
            {   // E1: M=64 (16 batch x 4 steps), N=256, K=32
                const int nt0 = 2 * w, nt1 = 2 * w + 1;
                half8 bv0 = *(const half8*)(w1P + ((size_t)nt0 * 64 + l) * 8);
                half8 bv1 = *(const half8*)(w1P + ((size_t)nt1 * 64 + l) * 8);
                f32x4 e[4][2];
                #pragma unroll
                for (int mt = 0; mt < 4; ++mt) {
                    half8 av = *(const half8*)&xbf64[mt * 16 + l15][lq * 8];
                    e[mt][0] = MFMA16(av, bv0, fz);
                    e[mt][1] = MFMA16(av, bv1, fz);
                }
                __syncthreads();
                #pragma unroll
                for (int mt = 0; mt < 4; ++mt)
                    #pragma unroll
                    for (int i = 0; i < 4; ++i) {
                        int m64 = mt * 16 + lq * 4 + i;
                        int n0 = nt0 * 16 + l15, n1 = nt1 * 16 + l15;
                        z1bf64[m64][n0] = f2h(fmaxf(e[mt][0][i] + eb1L[n0], 0.f));
                        z1bf64[m64][n1] = f2h(fmaxf(e[mt][1][i] + eb1L[n1], 0.f));
                    }
            }
            __syncthreads();
            {   // E2: M=64, N=256, K=256 -> latbuf (global)
                const int nt0 = 2 * w, nt1 = 2 * w + 1;
                f32x4 e[4][2];
                #pragma unroll
                for (int mt = 0; mt < 4; ++mt) { e[mt][0] = fz; e[mt][1] = fz; }
                #pragma unroll
                for (int kt = 0; kt < 8; ++kt) {
                    half8 bv0 = *(const half8*)(w2P + ((size_t)(nt0 * 8 + kt) * 64 + l) * 8);
                    half8 bv1 = *(const half8*)(w2P + ((size_t)(nt1 * 8 + kt) * 64 + l) * 8);
                    #pragma unroll
                    for (int mt = 0; mt < 4; ++mt) {
                        half8 av = *(const half8*)&z1bf64[mt * 16 + l15][kt * 32 + lq * 8];
                        e[mt][0] = MFMA16(av, bv0, e[mt][0]);
                        e[mt][1] = MFMA16(av, bv1, e[mt][1]);
                    }
                }
                #pragma unroll
                for (int mt = 0; mt < 4; ++mt)
                    #pragma unroll
                    for (int i = 0; i < 4; ++i) {
                        int b = lq * 4 + i;      // batch-in-16 ; cc = mt
                        int n0 = nt0 * 16 + l15, n1 = nt1 * 16 + l15;
                        size_t rb = ((size_t)(eb0 + b) * 4 + mt) * 256;
                        latbuf[rb + n0] = f2h(fmaxf(e[mt][0][i] + eb2L[n0], 0.f));
                        latbuf[rb + n1] = f2h(fmaxf(e[mt][1][i] + eb2L[n1], 0.f));
                    }
            }
            group_barrier(&chunkctr[c]);
        }

        const int rp = s & 1, wp = rp ^ 1;
        const unsigned short* hrd = hb[rp];
        unsigned short*       hwr = hb[wp];

        // ================= heads(s-1) + dp(s-1) =================
        if (s > 0) {
            f32x4 hc = fz;
            const int ka = 2 * w, kb = 2 * w + 1;
            half8 a0 = *(const half8*)(hrd + (size_t)(eb0 + l15) * 512 + ka * 32 + lq * 8);
            half8 b0 = *(const half8*)(headP + ((size_t)ka * 64 + l) * 8);
            half8 a1 = *(const half8*)(hrd + (size_t)(eb0 + l15) * 512 + kb * 32 + lq * 8);
            half8 b1 = *(const half8*)(headP + ((size_t)kb * 64 + l) * 8);
            hc = MFMA16(a0, b0, hc);
            hc = MFMA16(a1, b1, hc);
            #pragma unroll
            for (int i = 0; i < 4; ++i) sdotP[w][lq * 4 + i][l15] = hc[i];
            __syncthreads();
            if (t < BT) {
                const int b = t;
                float sd[10];
                #pragma unroll
                for (int d = 0; d < 10; ++d) {
                    float acc = 0.f;
                    #pragma unroll
                    for (int w8 = 0; w8 < 8; ++w8) acc += sdotP[w8][b][d];
                    sd[d] = acc;
                }
                const float* xp = x + ((size_t)(eb0 + b) * T_STEPS + (s - 1)) * IN_DIM;
                float ax = xp[0], ay = xp[1], az = xp[2], dtv = xp[16];
                float q0 = sd[0] + q_b[0], q1 = sd[1] + q_b[1];
                float q2 = sd[2] + q_b[2], q3 = sd[3] + q_b[3];
                float nrm = fmaxf(sqrtf(q0*q0 + q1*q1 + q2*q2 + q3*q3), 1e-12f);
                float qw = q0/nrm, qx = q1/nrm, qy = q2/nrm, qz = q3/nrm;
                float vx = sd[4] + v_b[0], vy = sd[5] + v_b[1], vz = sd[6] + v_b[2];
                float ex = sd[7] + c_b[0], ey = sd[8] + c_b[1], ez = sd[9] + c_b[2];
                float xx = qx*qx, yy = qy*qy, zz = qz*qz;
                float xy = qx*qy, xz = qx*qz, yz = qy*qz;
                float wxq = qw*qx, wyq = qw*qy, wzq = qw*qz;
                float aw0 = (1.f - 2.f*(yy+zz))*ax + 2.f*(xy-wzq)*ay + 2.f*(xz+wyq)*az;
                float aw1 = 2.f*(xy+wzq)*ax + (1.f - 2.f*(xx+zz))*ay + 2.f*(yz-wxq)*az;
                float aw2 = 2.f*(xz-wyq)*ax + 2.f*(yz+wxq)*ay + (1.f - 2.f*(xx+yy))*az;
                float hdt2 = 0.5f * dtv * dtv;
                dp0 += vx*dtv + aw0*hdt2 + ex;
                dp1 += vy*dtv + aw1*hdt2 + ey;
                dp2 += vz*dtv + aw2*hdt2 + ez;
            }
        }

        // ================= gate GEMM: M=512, N=48, K=768 =================
        {
            f32x4 aR[4], aZ[4], aNi[4], aNh[4];
            #pragma unroll
            for (int mt = 0; mt < 4; ++mt) {
                aR[mt] = fz; aZ[mt] = fz; aNi[mt] = fz; aNh[mt] = fz;
            }
            const unsigned short* latp = latbuf + (r0 * 4 + cs) * 256 + lq * 8;
            const unsigned short* hp   = hrd + r0 * 512 + lq * 8;

#define LDA(dst, ktv)                                                           \
            { _Pragma("unroll")                                                 \
              for (int mt = 0; mt < 4; ++mt)                                    \
                  dst[mt] = ((ktv) < 8)                                         \
                    ? *(const half8*)(latp + (size_t)mt * (16 * 4 * 256) + (ktv) * 32)      \
                    : *(const half8*)(hp   + (size_t)mt * (16 * 512) + ((ktv) - 8) * 32); }
#define LDB(dst, ktv)                                                           \
            { _Pragma("unroll")                                                 \
              for (int gg = 0; gg < 3; ++gg)                                    \
                  dst[gg] = *(const half8*)&wgL[(((ktv) * 3 + gg) * 64 + l) * 8]; }
#define DOMF(A, B, ktv)                                                         \
            { _Pragma("unroll")                                                 \
              for (int mt = 0; mt < 4; ++mt) {                                  \
                  aR[mt] = MFMA16(A[mt], B[0], aR[mt]);                         \
                  aZ[mt] = MFMA16(A[mt], B[1], aZ[mt]);                         \
                  if ((ktv) < 8) aNi[mt] = MFMA16(A[mt], B[2], aNi[mt]);        \
                  else           aNh[mt] = MFMA16(A[mt], B[2], aNh[mt]); } }

            half8 aF[2][4], bF[2][3];
            LDA(aF[0], 0); LDB(bF[0], 0);
            #pragma unroll
            for (int kt = 0; kt < 24; ++kt) {
                const int cur = kt & 1, nx = cur ^ 1;
                if (kt < 23) { LDA(aF[nx], kt + 1); LDB(bF[nx], kt + 1); }
                DOMF(aF[cur], bF[cur], kt);
            }
#undef LDA
#undef LDB
#undef DOMF
            // gate nonlinearity + h_new write
            #pragma unroll
            for (int mt = 0; mt < 4; ++mt) {
                #pragma unroll
                for (int i = 0; i < 4; ++i) {
                    const size_t row = (size_t)(g * 512 + w * 64 + mt * 16 + lq * 4 + i);
                    float dtv = dtbuf[row * 4 + cs];
                    float gr = aR[mt][i]  + bR  + dtv * wr2;
                    float gz = aZ[mt][i]  + bZ  + dtv * wz2;
                    float gi = aNi[mt][i] + bIN + dtv * wn2;
                    float gh = aNh[mt][i] + bHN;
                    float r  = 1.f / (1.f + __expf(-gr));
                    float zg = 1.f / (1.f + __expf(-gz));
                    float narg = gi + r * gh;
                    float n  = 1.f - 2.f / (__expf(2.f * narg) + 1.f);
                    float hn = (1.f - zg) * n + zg * ho[mt][i];
                    ho[mt][i] = hn;
                    hwr[row * 512 + jd] = f2h(hn);
                }
            }
        }
        group_barrier(&stepctr[s]);
    }

    // ================= epilogue: heads(T-1) + dp(T-1) + store =================
    {
        const unsigned short* hrd = hb[T_STEPS & 1];
        f32x4 hc = fz;
        const int ka = 2 * w, kb = 2 * w + 1;
        half8 a0 = *(const half8*)(hrd + (size_t)(eb0 + l15) * 512 + ka * 32 + lq * 8);
        half8 b0 = *(const half8*)(headP + ((size_t)ka * 64 + l) * 8);
        half8 a1 = *(const half8*)(hrd + (size_t)(eb0 + l15) * 512 + kb * 32 + lq * 8);
        half8 b1 = *(const half8*)(headP + ((size_t)kb * 64 + l) * 8);
        hc = MFMA16(a0, b0, hc);
        hc = MFMA16(a1, b1, hc);
        #pragma unroll
        for (int i = 0; i < 4; ++i) sdotP[w][lq * 4 + i][l15] = hc[i];
    }
    __syncthreads();
    if (t < BT) {
        const int b = t;
        float sd[10];
        #pragma unroll
        for (int d = 0; d < 10; ++d) {
            float acc = 0.f;
            #pragma unroll
            for (int w8 = 0; w8 < 8; ++w8) acc += sdotP[w8][b][d];
            sd[d] = acc;
        }
        const float* xp = x + ((size_t)(eb0 + b) * T_STEPS + (T_STEPS - 1)) * IN_DIM;
        float ax = xp[0], ay = xp[1], az = xp[2], dtv = xp[16];
        float q0 = sd[0] + q_b[0], q1 = sd[1] + q_b[1];
        float q2 = sd[2] + q_b[2], q3 = sd[3] + q_b[3];
        float nrm = fmaxf(sqrtf(q0*q0 + q1*q1 + q2*q2 + q3*q3), 1e-12f);
        float qw = q0/nrm, qx = q1/nrm, qy = q2/nrm, qz = q3/nrm;
        float vx = sd[4] + v_b[0], vy = sd[5] + v_b[1], vz = sd[6] + v_b[2];
        float ex = sd[7] + c_b[0], ey = sd[8] + c_b[1], ez = sd[9] + c_b[2];
        float xx = qx*qx, yy = qy*qy, zz = qz*qz;
        float xy = qx*qy, xz = qx*qz, yz = qy*qz;
        float wxq = qw*qx, wyq = qw*qy, wzq = qw*qz;
        float aw0 = (1.f - 2.f*(yy+zz))*ax + 2.f*(xy-wzq)*ay + 2.f*(xz+wyq)*az;
        float aw1 = 2.f*(xy+wzq)*ax + (1.f - 2.f*(xx+zz))*ay + 2.f*(yz-wxq)*az;
        float aw2 = 2.f*(xz-wyq)*ax + 2.f*(yz+wxq)*ay + (1.f - 2.f*(xx+yy))*az;
        float hdt2 = 0.5f * dtv * dtv;
        dp0 += vx*dtv + aw0*hdt2 + ex;
        dp1 += vy*dtv + aw1*hdt2 + ey;
        dp2 += vz*dtv + aw2*hdt2 + ez;
        out[(size_t)(eb0 + b) * 3 + 0] = dp0;
        out[(size_t)(eb0 + b) * 3 + 1] = dp1;
        out[(size_t)(eb0 + b) * 3 + 2] = dp2;
    }
}

extern "C" void kernel_launch(void* const* d_in, const int* in_sizes, int n_in,
                              void* d_out, int out_size, void* d_ws, size_t ws_size,
                              hipStream_t stream) {
    const float* x      = (const float*)d_in[0];
    const float* h0     = (const float*)d_in[1];
    const float* enc_w1 = (const float*)d_in[2];
    const float* enc_b1 = (const float*)d_in[3];
    const float* enc_w2 = (const float*)d_in[4];
    const float* enc_b2 = (const float*)d_in[5];
    const float* w_ih   = (const float*)d_in[6];
    const float* w_hh   = (const float*)d_in[7];
    const float* b_ih   = (const float*)d_in[8];
    const float* b_hh   = (const float*)d_in[9];
    const float* q_w    = (const float*)d_in[10];
    const float* q_b    = (const float*)d_in[11];
    const float* v_w    = (const float*)d_in[12];
    const float* v_b    = (const float*)d_in[13];
    const float* c_w    = (const float*)d_in[14];
    const float* c_b    = (const float*)d_in[15];
    unsigned char* ws = (unsigned char*)d_ws;
    float* out = (float*)d_out;

    hipLaunchKernelGGL(pack_kernel, dim3(2048), dim3(256), 0, stream,
                       enc_w1, enc_w2, w_ih, w_hh, b_ih, b_hh, q_w, v_w, c_w, h0, ws);

    void* args[] = { (void*)&x, (void*)&h0, (void*)&enc_b1, (void*)&enc_b2,
                     (void*)&q_b, (void*)&v_b, (void*)&c_b, (void*)&ws, (void*)&out };
    (void)hipLaunchCooperativeKernel((void*)imu_coop_kernel, dim3(256), dim3(NTH),
                                     args, 0, stream);
}